// Round 2
// baseline (862.867 us; speedup 1.0000x reference)
//
#include <hip/hip_runtime.h>
#include <hip/hip_bf16.h>

#define NN 8
#define HH 56
#define WW 56
#define C1 256
#define CM 128
#define C2 256
#define GG 4
#define K2K 9
#define HWSZ (HH*WW)            // 3136
#define LL (NN*HWSZ)            // 25088
#define EPSF 1e-5f

// ---------------- K0: transpose cv1 weights (co,ci,tap) -> (ci,tap,co) ----------------
__global__ void k0_wt(const float* __restrict__ w, float* __restrict__ wt){
    int d = blockIdx.x*256 + threadIdx.x;
    if (d >= C1*CM*9) return;
    int co  = d & (CM-1);
    int tmp = d >> 7;
    int tap = tmp % 9;
    int ci  = tmp / 9;
    wt[d] = w[(co*C1 + ci)*9 + tap];
}

// ---------------- K1: 3x3 conv 256->128 + BN + SiLU, writes h NHWC f32 ----------------
// block = 128 threads (one per co), handles (n, y, 8 consecutive x)
__global__ __launch_bounds__(128) void k1_conv(
    const float* __restrict__ x, const float* __restrict__ wt,
    const float* __restrict__ bg, const float* __restrict__ bb,
    const float* __restrict__ bm, const float* __restrict__ bv,
    float* __restrict__ h)
{
    __shared__ float patch[C1*30];   // 256 ci x 3 rows x 10 cols
    int bid = blockIdx.x;
    int xt = bid % 7;
    int y  = (bid/7) % HH;
    int n  = bid / (7*HH);
    int tid = threadIdx.x;
    int x0 = xt*8;
    for (int e = tid; e < C1*30; e += 128){
        int ci = e / 30;
        int r  = (e % 30) / 10;
        int c  = e % 10;
        int yy = y + r - 1;
        int xx = x0 + c - 1;
        float v = 0.f;
        if (yy >= 0 && yy < HH && xx >= 0 && xx < WW)
            v = x[((size_t)(n*C1 + ci)*HH + yy)*WW + xx];
        patch[e] = v;
    }
    __syncthreads();
    int co = tid;
    float acc[8] = {0.f,0.f,0.f,0.f,0.f,0.f,0.f,0.f};
    for (int ci = 0; ci < C1; ci++){
        const float* wrow = wt + (size_t)ci*9*CM + co;
        const float* prow = patch + ci*30;
        #pragma unroll
        for (int dy = 0; dy < 3; dy++){
            float rr[10];
            #pragma unroll
            for (int c = 0; c < 10; c++) rr[c] = prow[dy*10 + c];
            float w0 = wrow[(dy*3+0)*CM];
            float w1 = wrow[(dy*3+1)*CM];
            float w2 = wrow[(dy*3+2)*CM];
            #pragma unroll
            for (int p = 0; p < 8; p++)
                acc[p] += w0*rr[p] + w1*rr[p+1] + w2*rr[p+2];
        }
    }
    float sc = bg[co] * rsqrtf(bv[co] + EPSF);
    float bi = bb[co] - bm[co] * sc;
    #pragma unroll
    for (int p = 0; p < 8; p++){
        float z = acc[p]*sc + bi;
        float s = z / (1.f + expf(-z));
        h[((size_t)(n*HH + y)*WW + (x0+p))*CM + co] = s;
    }
}

// ---------------- K2: depthwise 3x3 + bias -> LayerNorm(128) -> exact GELU, writes t NHWC f32 ----------------
__global__ __launch_bounds__(128) void k2_dwlngelu(
    const float* __restrict__ h, const float* __restrict__ wdw, const float* __restrict__ bdw,
    const float* __restrict__ lng, const float* __restrict__ lnb, float* __restrict__ t)
{
    int pix = blockIdx.x;
    int n = pix / HWSZ;
    int rem = pix % HWSZ;
    int y = rem / WW, xq = rem % WW;
    int c = threadIdx.x;
    float acc = bdw[c];
    #pragma unroll
    for (int tap = 0; tap < 9; tap++){
        int dy = tap/3, dx = tap%3;
        int yy = y+dy-1, xx = xq+dx-1;
        if (yy>=0 && yy<HH && xx>=0 && xx<WW)
            acc += h[((size_t)(n*HH+yy)*WW+xx)*CM + c] * wdw[c*9+tap];
    }
    float s = acc, ss = acc*acc;
    #pragma unroll
    for (int off=32; off; off>>=1){ s += __shfl_down(s,off); ss += __shfl_down(ss,off); }
    __shared__ float red[4];
    if ((c & 63) == 0){ red[(c>>6)*2] = s; red[(c>>6)*2+1] = ss; }
    __syncthreads();
    float tot  = red[0]+red[2];
    float tots = red[1]+red[3];
    float mean = tot * (1.f/CM);
    float var  = tots*(1.f/CM) - mean*mean;
    var = fmaxf(var, 0.f);
    float z = (acc-mean)*rsqrtf(var+EPSF)*lng[c] + lnb[c];
    float g = 0.5f*z*(1.f + erff(z*0.70710678118654752f));
    t[(size_t)pix*CM + c] = g;
}

// ---------------- K3: value/offset/mask projections + softmax ----------------
__global__ __launch_bounds__(128) void k3_proj(
    const float* __restrict__ h, const float* __restrict__ t,
    const float* __restrict__ winp, const float* __restrict__ binp,
    const float* __restrict__ woff, const float* __restrict__ boff,
    const float* __restrict__ wmsk, const float* __restrict__ bmsk,
    float* __restrict__ val, float* __restrict__ off, float* __restrict__ msk)
{
    int pix = blockIdx.x;
    int c = threadIdx.x;
    __shared__ float hb[CM], tb[CM], mb[GG*K2K];
    hb[c] = h[(size_t)pix*CM + c];
    tb[c] = t[(size_t)pix*CM + c];
    __syncthreads();
    float a = binp[c];
    for (int ci=0; ci<CM; ci++) a += hb[ci]*winp[ci*CM + c];
    val[(size_t)pix*CM + c] = a;
    if (c < 72){
        float ao = boff[c];
        for (int ci=0; ci<CM; ci++) ao += tb[ci]*woff[ci*72 + c];
        off[(size_t)pix*72 + c] = ao;
    }
    if (c < 36){
        float am = bmsk[c];
        for (int ci=0; ci<CM; ci++) am += tb[ci]*wmsk[ci*36 + c];
        mb[c] = am;
    }
    __syncthreads();
    if (c < 36){
        int g0 = (c/9)*9;
        float mx = mb[g0];
        #pragma unroll
        for (int j=1;j<9;j++) mx = fmaxf(mx, mb[g0+j]);
        float sum = 0.f;
        #pragma unroll
        for (int j=0;j<9;j++) sum += expf(mb[g0+j]-mx);
        msk[(size_t)pix*36 + c] = expf(mb[c]-mx)/sum;
    }
}

// ---------------- K4: DCNv3 bilinear sample + output proj + BN2 + SiLU + residual ----------------
__global__ __launch_bounds__(128) void k4_dcn_out(
    const float* __restrict__ val, const float* __restrict__ off, const float* __restrict__ msk,
    const float* __restrict__ wout, const float* __restrict__ bout,
    const float* __restrict__ g2, const float* __restrict__ bb2,
    const float* __restrict__ m2, const float* __restrict__ v2,
    const float* __restrict__ xin, float* __restrict__ out)
{
    int pix = blockIdx.x;
    int n = pix / HWSZ;
    int rem = pix % HWSZ;
    int y = rem / WW, xq = rem % WW;
    int c = threadIdx.x;
    __shared__ float ob[GG*K2K*2], mk[GG*K2K], osm[CM];
    if (c < 72) ob[c] = off[(size_t)pix*72 + c];
    else if (c < 108) mk[c-72] = msk[(size_t)pix*36 + (c-72)];
    __syncthreads();
    int g = c >> 5;
    float acc = 0.f;
    #pragma unroll
    for (int k=0;k<9;k++){
        float oxv = ob[g*18 + k*2];
        float oyv = ob[g*18 + k*2 + 1];
        // kgrid: k=(i*3+j), x uses i=k/3, y uses j=k%3 (meshgrid 'ij' in reference)
        float sx = (float)xq + (float)(k/3) - 1.f + oxv;
        float sy = (float)y  + (float)(k%3) - 1.f + oyv;
        float x0f = floorf(sx), y0f = floorf(sy);
        float fx = sx - x0f, fy = sy - y0f;
        int x0 = (int)x0f, y0 = (int)y0f;
        float mw = mk[g*9+k];
        float w00 = (1.f-fy)*(1.f-fx)*mw;
        float w01 = (1.f-fy)*fx*mw;
        float w10 = fy*(1.f-fx)*mw;
        float w11 = fy*fx*mw;
        if ((unsigned)y0     < HH && (unsigned)x0     < WW) acc += w00*val[((size_t)(n*HH+y0  )*WW+x0  )*CM + c];
        if ((unsigned)y0     < HH && (unsigned)(x0+1) < WW) acc += w01*val[((size_t)(n*HH+y0  )*WW+x0+1)*CM + c];
        if ((unsigned)(y0+1) < HH && (unsigned)x0     < WW) acc += w10*val[((size_t)(n*HH+y0+1)*WW+x0  )*CM + c];
        if ((unsigned)(y0+1) < HH && (unsigned)(x0+1) < WW) acc += w11*val[((size_t)(n*HH+y0+1)*WW+x0+1)*CM + c];
    }
    osm[c] = acc;
    __syncthreads();
    #pragma unroll
    for (int r=0; r<2; r++){
        int c2 = c + r*CM;
        float a2 = bout[c2];
        for (int cm=0; cm<CM; cm++) a2 += osm[cm]*wout[cm*C2 + c2];
        float sc = g2[c2]*rsqrtf(v2[c2]+EPSF);
        float bi = bb2[c2] - m2[c2]*sc;
        float z = a2*sc + bi;
        float sl = z/(1.f+expf(-z));
        size_t oidx = ((size_t)(n*C2 + c2)*HH + y)*WW + xq;
        out[oidx] = sl + xin[oidx];
    }
}

extern "C" void kernel_launch(void* const* d_in, const int* in_sizes, int n_in,
                              void* d_out, int out_size, void* d_ws, size_t ws_size,
                              hipStream_t stream)
{
    const float* x    = (const float*)d_in[0];
    const float* wcv1 = (const float*)d_in[1];
    const float* bn1g = (const float*)d_in[2];
    const float* bn1b = (const float*)d_in[3];
    const float* bn1m = (const float*)d_in[4];
    const float* bn1v = (const float*)d_in[5];
    const float* wdw  = (const float*)d_in[6];
    const float* bdw  = (const float*)d_in[7];
    const float* lng  = (const float*)d_in[8];
    const float* lnb  = (const float*)d_in[9];
    const float* winp = (const float*)d_in[10];
    const float* binp = (const float*)d_in[11];
    const float* woff = (const float*)d_in[12];
    const float* boff = (const float*)d_in[13];
    const float* wmsk = (const float*)d_in[14];
    const float* bmsk = (const float*)d_in[15];
    const float* wout = (const float*)d_in[16];
    const float* bout = (const float*)d_in[17];
    const float* bn2g = (const float*)d_in[18];
    const float* bn2b = (const float*)d_in[19];
    const float* bn2m = (const float*)d_in[20];
    const float* bn2v = (const float*)d_in[21];

    float* ws  = (float*)d_ws;
    float* w1t = ws;                                   // 294,912 f32
    float* h   = w1t + (size_t)C1*CM*9;                // 3,211,264 f32
    float* t   = h   + (size_t)LL*CM;                  // 3,211,264 f32
    float* val = t   + (size_t)LL*CM;                  // 3,211,264 f32
    float* off = val + (size_t)LL*CM;                  // 1,806,336 f32
    float* msk = off + (size_t)LL*72;                  //   903,168 f32

    hipLaunchKernelGGL(k0_wt,   dim3((C1*CM*9+255)/256), dim3(256), 0, stream, wcv1, w1t);
    hipLaunchKernelGGL(k1_conv, dim3(NN*HH*7), dim3(128), 0, stream,
                       x, w1t, bn1g, bn1b, bn1m, bn1v, h);
    hipLaunchKernelGGL(k2_dwlngelu, dim3(LL), dim3(128), 0, stream,
                       h, wdw, bdw, lng, lnb, t);
    hipLaunchKernelGGL(k3_proj, dim3(LL), dim3(128), 0, stream,
                       h, t, winp, binp, woff, boff, wmsk, bmsk, val, off, msk);
    hipLaunchKernelGGL(k4_dcn_out, dim3(LL), dim3(128), 0, stream,
                       val, off, msk, wout, bout, bn2g, bn2b, bn2m, bn2v, x,
                       (float*)d_out);
}

// Round 3
// 513.409 us; speedup vs baseline: 1.6807x; 1.6807x over previous
//
#include <hip/hip_runtime.h>
#include <hip/hip_bf16.h>

typedef __hip_bfloat16 bf16;
typedef float f32x4 __attribute__((ext_vector_type(4)));
typedef short s16x8 __attribute__((ext_vector_type(8)));

#define NN 8
#define HH 56
#define WW 56
#define C1 256
#define CM 128
#define C2 256
#define GG 4
#define K2K 9
#define HWSZ (HH*WW)            // 3136
#define LL (NN*HWSZ)            // 25088
#define EPSF 1e-5f
#define XP_H 58
#define XP_W 58

// ---------------- K0z: zero xp (padded NHWC bf16 input) ----------------
__global__ void k0z(float4* __restrict__ p, int n4){
    int i = blockIdx.x*256 + threadIdx.x;
    if (i < n4) p[i] = make_float4(0.f,0.f,0.f,0.f);
}

// ---------------- K0a: x NCHW f32 -> xp padded NHWC bf16 (LDS transpose) ----------------
__global__ __launch_bounds__(256) void k0a(const float* __restrict__ x, bf16* __restrict__ xp){
    __shared__ float lds[64][57];
    int bid = blockIdx.x;
    int n = bid / 224; int rem = bid % 224;
    int y = rem >> 2; int ci0 = (rem & 3) << 6;
    int tid = threadIdx.x;
    for (int e = tid; e < 64*56; e += 256){
        int ci = e / 56, xx = e - ci*56;
        lds[ci][xx] = x[((size_t)((n*C1 + ci0 + ci)*HH) + y)*WW + xx];
    }
    __syncthreads();
    for (int e = tid; e < 64*56; e += 256){
        int xx = e >> 6, ci = e & 63;
        xp[((size_t)(n*XP_H + y + 1)*XP_W + (xx + 1))*C1 + ci0 + ci] = __float2bfloat16(lds[ci][xx]);
    }
}

// ---------------- K0w: cv1 weights -> MFMA B-fragment layout bf16 ----------------
// Wf[(kt*8+nt)*64+lane][j] = W[k][co], k=kt*32+(lane>>4)*8+j (k=tap*256+ci), co=nt*16+(lane&15)
__global__ void k0w(const float* __restrict__ w, bf16* __restrict__ Wf){
    int tlin = blockIdx.x*256 + threadIdx.x;   // 36864 total
    int kt  = tlin >> 9;
    int rem = tlin & 511;
    int nt  = rem >> 6;
    int lane = rem & 63;
    int co = nt*16 + (lane & 15);
    int kbase = kt*32 + (lane >> 4)*8;
    bf16* dst = Wf + (size_t)tlin*8;
    #pragma unroll
    for (int j = 0; j < 8; j++){
        int k = kbase + j;
        int tap = k >> 8;
        int ci  = k & 255;
        dst[j] = __float2bfloat16(w[((size_t)co*C1 + ci)*9 + tap]);
    }
}

// ---------------- K1: implicit-GEMM 3x3 conv via MFMA + BN + SiLU -> h NHWC f32 ----------------
__device__ __forceinline__ void stageB(const bf16* __restrict__ Wf, int s, bf16* buf, int w, int lane){
    const bf16* g = Wf + ((size_t)s << 12) + (w << 10) + lane*8;
    bf16* l = buf + (w << 10);
    __builtin_amdgcn_global_load_lds((const __attribute__((address_space(1))) void*)g,
                                     (__attribute__((address_space(3))) void*)l, 16, 0, 0);
    __builtin_amdgcn_global_load_lds((const __attribute__((address_space(1))) void*)(g + 512),
                                     (__attribute__((address_space(3))) void*)(l + 512), 16, 0, 0);
}

__device__ __forceinline__ s16x8 loadA(const bf16* __restrict__ xp, int browbase, int px, int s, int kpart){
    int tap = s >> 3;
    int dy = tap / 3;
    int dx = tap - dy*3;
    int ci0 = (s & 7) << 5;
    size_t off = ((size_t)((browbase + dy) * XP_W) + (px + dx)) * (size_t)C1 + ci0 + kpart*8;
    return *(const s16x8*)(xp + off);
}

__global__ __launch_bounds__(256) void k1_mfma(
    const bf16* __restrict__ xp, const bf16* __restrict__ Wf,
    const float* __restrict__ bg, const float* __restrict__ bb,
    const float* __restrict__ bm, const float* __restrict__ bv,
    float* __restrict__ h)
{
    __shared__ __align__(16) bf16 Bbuf[2][4096];   // 2 x 8 KB
    int bid = blockIdx.x;
    int n = bid / 112, rem = bid % 112;
    int y = rem >> 1, tile = rem & 1;
    int x0t = tile ? 24 : 0;                // x-tiles [0,32) and [24,56): overlap double-write is bitwise identical
    int tid = threadIdx.x, lane = tid & 63;
    int w  = tid >> 6;
    int wm = w & 1, wn = w >> 1;
    int kpart = lane >> 4;
    int pxA = x0t + wm*16 + (lane & 15);    // <= 55 by construction
    int browbase = n * XP_H + y;

    f32x4 acc[4] = {{0,0,0,0},{0,0,0,0},{0,0,0,0},{0,0,0,0}};

    stageB(Wf, 0, &Bbuf[0][0], w, lane);
    s16x8 a_cur = loadA(xp, browbase, pxA, 0, kpart);
    __syncthreads();

    for (int s = 0; s < 72; ++s){
        s16x8 a_nxt = a_cur;
        if (s + 1 < 72){
            stageB(Wf, s+1, &Bbuf[(s+1)&1][0], w, lane);
            a_nxt = loadA(xp, browbase, pxA, s+1, kpart);
        }
        const bf16* bufp = &Bbuf[s&1][0] + (wn << 11) + lane*8;
        #pragma unroll
        for (int ct = 0; ct < 4; ++ct){
            s16x8 bfrag = *(const s16x8*)(bufp + (ct << 9));
            acc[ct] = __builtin_amdgcn_mfma_f32_16x16x32_bf16(a_cur, bfrag, acc[ct], 0, 0, 0);
        }
        __syncthreads();
        a_cur = a_nxt;
    }

    // epilogue: BN + SiLU, C-layout: col=lane&15 (co), row=kpart*4+r (pixel)
    int pxO = x0t + wm*16 + kpart*4;
    size_t rowbase = ((size_t)(n*HH + y))*WW;
    #pragma unroll
    for (int ct = 0; ct < 4; ++ct){
        int co = (wn << 6) + (ct << 4) + (lane & 15);
        float sc = bg[co] * rsqrtf(bv[co] + EPSF);
        float bi = bb[co] - bm[co]*sc;
        #pragma unroll
        for (int r = 0; r < 4; ++r){
            float z = acc[ct][r]*sc + bi;
            float sl = z / (1.f + expf(-z));
            h[(rowbase + pxO + r)*CM + co] = sl;
        }
    }
}

// ---------------- K2: depthwise 3x3 + bias -> LayerNorm(128) -> exact GELU ----------------
__global__ __launch_bounds__(128) void k2_dwlngelu(
    const float* __restrict__ h, const float* __restrict__ wdw, const float* __restrict__ bdw,
    const float* __restrict__ lng, const float* __restrict__ lnb, float* __restrict__ t)
{
    int pix = blockIdx.x;
    int n = pix / HWSZ;
    int rem = pix % HWSZ;
    int y = rem / WW, xq = rem % WW;
    int c = threadIdx.x;
    float acc = bdw[c];
    #pragma unroll
    for (int tap = 0; tap < 9; tap++){
        int dy = tap/3, dx = tap%3;
        int yy = y+dy-1, xx = xq+dx-1;
        if (yy>=0 && yy<HH && xx>=0 && xx<WW)
            acc += h[((size_t)(n*HH+yy)*WW+xx)*CM + c] * wdw[c*9+tap];
    }
    float s = acc, ss = acc*acc;
    #pragma unroll
    for (int off=32; off; off>>=1){ s += __shfl_down(s,off); ss += __shfl_down(ss,off); }
    __shared__ float red[4];
    if ((c & 63) == 0){ red[(c>>6)*2] = s; red[(c>>6)*2+1] = ss; }
    __syncthreads();
    float tot  = red[0]+red[2];
    float tots = red[1]+red[3];
    float mean = tot * (1.f/CM);
    float var  = tots*(1.f/CM) - mean*mean;
    var = fmaxf(var, 0.f);
    float z = (acc-mean)*rsqrtf(var+EPSF)*lng[c] + lnb[c];
    float g = 0.5f*z*(1.f + erff(z*0.70710678118654752f));
    t[(size_t)pix*CM + c] = g;
}

// ---------------- K3: value/offset/mask projections + softmax ----------------
__global__ __launch_bounds__(128) void k3_proj(
    const float* __restrict__ h, const float* __restrict__ t,
    const float* __restrict__ winp, const float* __restrict__ binp,
    const float* __restrict__ woff, const float* __restrict__ boff,
    const float* __restrict__ wmsk, const float* __restrict__ bmsk,
    float* __restrict__ val, float* __restrict__ off, float* __restrict__ msk)
{
    int pix = blockIdx.x;
    int c = threadIdx.x;
    __shared__ float hb[CM], tb[CM], mb[GG*K2K];
    hb[c] = h[(size_t)pix*CM + c];
    tb[c] = t[(size_t)pix*CM + c];
    __syncthreads();
    float a = binp[c];
    for (int ci=0; ci<CM; ci++) a += hb[ci]*winp[ci*CM + c];
    val[(size_t)pix*CM + c] = a;
    if (c < 72){
        float ao = boff[c];
        for (int ci=0; ci<CM; ci++) ao += tb[ci]*woff[ci*72 + c];
        off[(size_t)pix*72 + c] = ao;
    }
    if (c < 36){
        float am = bmsk[c];
        for (int ci=0; ci<CM; ci++) am += tb[ci]*wmsk[ci*36 + c];
        mb[c] = am;
    }
    __syncthreads();
    if (c < 36){
        int g0 = (c/9)*9;
        float mx = mb[g0];
        #pragma unroll
        for (int j=1;j<9;j++) mx = fmaxf(mx, mb[g0+j]);
        float sum = 0.f;
        #pragma unroll
        for (int j=0;j<9;j++) sum += expf(mb[g0+j]-mx);
        msk[(size_t)pix*36 + c] = expf(mb[c]-mx)/sum;
    }
}

// ---------------- K4: DCNv3 bilinear sample + output proj + BN2 + SiLU + residual ----------------
__global__ __launch_bounds__(128) void k4_dcn_out(
    const float* __restrict__ val, const float* __restrict__ off, const float* __restrict__ msk,
    const float* __restrict__ wout, const float* __restrict__ bout,
    const float* __restrict__ g2, const float* __restrict__ bb2,
    const float* __restrict__ m2, const float* __restrict__ v2,
    const float* __restrict__ xin, float* __restrict__ out)
{
    int pix = blockIdx.x;
    int n = pix / HWSZ;
    int rem = pix % HWSZ;
    int y = rem / WW, xq = rem % WW;
    int c = threadIdx.x;
    __shared__ float ob[GG*K2K*2], mk[GG*K2K], osm[CM];
    if (c < 72) ob[c] = off[(size_t)pix*72 + c];
    else if (c < 108) mk[c-72] = msk[(size_t)pix*36 + (c-72)];
    __syncthreads();
    int g = c >> 5;
    float acc = 0.f;
    #pragma unroll
    for (int k=0;k<9;k++){
        float oxv = ob[g*18 + k*2];
        float oyv = ob[g*18 + k*2 + 1];
        float sx = (float)xq + (float)(k/3) - 1.f + oxv;
        float sy = (float)y  + (float)(k%3) - 1.f + oyv;
        float x0f = floorf(sx), y0f = floorf(sy);
        float fx = sx - x0f, fy = sy - y0f;
        int x0 = (int)x0f, y0 = (int)y0f;
        float mw = mk[g*9+k];
        float w00 = (1.f-fy)*(1.f-fx)*mw;
        float w01 = (1.f-fy)*fx*mw;
        float w10 = fy*(1.f-fx)*mw;
        float w11 = fy*fx*mw;
        if ((unsigned)y0     < HH && (unsigned)x0     < WW) acc += w00*val[((size_t)(n*HH+y0  )*WW+x0  )*CM + c];
        if ((unsigned)y0     < HH && (unsigned)(x0+1) < WW) acc += w01*val[((size_t)(n*HH+y0  )*WW+x0+1)*CM + c];
        if ((unsigned)(y0+1) < HH && (unsigned)x0     < WW) acc += w10*val[((size_t)(n*HH+y0+1)*WW+x0  )*CM + c];
        if ((unsigned)(y0+1) < HH && (unsigned)(x0+1) < WW) acc += w11*val[((size_t)(n*HH+y0+1)*WW+x0+1)*CM + c];
    }
    osm[c] = acc;
    __syncthreads();
    #pragma unroll
    for (int r=0; r<2; r++){
        int c2 = c + r*CM;
        float a2 = bout[c2];
        for (int cm=0; cm<CM; cm++) a2 += osm[cm]*wout[cm*C2 + c2];
        float sc = g2[c2]*rsqrtf(v2[c2]+EPSF);
        float bi = bb2[c2] - m2[c2]*sc;
        float z = a2*sc + bi;
        float sl = z/(1.f+expf(-z));
        size_t oidx = ((size_t)(n*C2 + c2)*HH + y)*WW + xq;
        out[oidx] = sl + xin[oidx];
    }
}

extern "C" void kernel_launch(void* const* d_in, const int* in_sizes, int n_in,
                              void* d_out, int out_size, void* d_ws, size_t ws_size,
                              hipStream_t stream)
{
    const float* x    = (const float*)d_in[0];
    const float* wcv1 = (const float*)d_in[1];
    const float* bn1g = (const float*)d_in[2];
    const float* bn1b = (const float*)d_in[3];
    const float* bn1m = (const float*)d_in[4];
    const float* bn1v = (const float*)d_in[5];
    const float* wdw  = (const float*)d_in[6];
    const float* bdw  = (const float*)d_in[7];
    const float* lng  = (const float*)d_in[8];
    const float* lnb  = (const float*)d_in[9];
    const float* winp = (const float*)d_in[10];
    const float* binp = (const float*)d_in[11];
    const float* woff = (const float*)d_in[12];
    const float* boff = (const float*)d_in[13];
    const float* wmsk = (const float*)d_in[14];
    const float* bmsk = (const float*)d_in[15];
    const float* wout = (const float*)d_in[16];
    const float* bout = (const float*)d_in[17];
    const float* bn2g = (const float*)d_in[18];
    const float* bn2b = (const float*)d_in[19];
    const float* bn2m = (const float*)d_in[20];
    const float* bn2v = (const float*)d_in[21];

    unsigned char* base = (unsigned char*)d_ws;
    bf16*  Wf  = (bf16*)base;                                  //   589,824 B
    float* h   = (float*)(base + 589824);                      // 12,845,056 B
    float* t   = h   + (size_t)LL*CM;                          // 12,845,056 B
    float* val = t   + (size_t)LL*CM;                          // 12,845,056 B
    float* off = val + (size_t)LL*CM;                          //  7,225,344 B
    float* msk = off + (size_t)LL*72;                          //  3,612,672 B
    bf16*  xp  = (bf16*)val;   // alias: xp (13.78 MB) lives in [val,off) region, dead before k3 writes them

    const int xp_f4 = (NN*XP_H*XP_W*C1*2) / 16;                // 861,184 float4
    hipLaunchKernelGGL(k0z, dim3((xp_f4+255)/256), dim3(256), 0, stream, (float4*)xp, xp_f4);
    hipLaunchKernelGGL(k0a, dim3(NN*HH*4), dim3(256), 0, stream, x, xp);
    hipLaunchKernelGGL(k0w, dim3(144), dim3(256), 0, stream, wcv1, Wf);
    hipLaunchKernelGGL(k1_mfma, dim3(NN*HH*2), dim3(256), 0, stream,
                       xp, Wf, bn1g, bn1b, bn1m, bn1v, h);
    hipLaunchKernelGGL(k2_dwlngelu, dim3(LL), dim3(128), 0, stream,
                       h, wdw, bdw, lng, lnb, t);
    hipLaunchKernelGGL(k3_proj, dim3(LL), dim3(128), 0, stream,
                       h, t, winp, binp, woff, boff, wmsk, bmsk, val, off, msk);
    hipLaunchKernelGGL(k4_dcn_out, dim3(LL), dim3(128), 0, stream,
                       val, off, msk, wout, bout, bn2g, bn2b, bn2m, bn2v, x,
                       (float*)d_out);
}

// Round 4
// 320.379 us; speedup vs baseline: 2.6933x; 1.6025x over previous
//
#include <hip/hip_runtime.h>
#include <hip/hip_bf16.h>

typedef __hip_bfloat16 bf16;
typedef float f32x4 __attribute__((ext_vector_type(4)));
typedef short s16x8 __attribute__((ext_vector_type(8)));

#define NN 8
#define HH 56
#define WW 56
#define C1 256
#define CM 128
#define C2 256
#define GG 4
#define K2K 9
#define HWSZ (HH*WW)            // 3136
#define LL (NN*HWSZ)            // 25088
#define EPSF 1e-5f
#define XP_H 58
#define XP_W 58

__device__ __forceinline__ float b2f(bf16 v){ return __bfloat162float(v); }

// ---------------- K0z: zero xp (padded NHWC bf16 input) ----------------
__global__ void k0z(float4* __restrict__ p, int n4){
    int i = blockIdx.x*256 + threadIdx.x;
    if (i < n4) p[i] = make_float4(0.f,0.f,0.f,0.f);
}

// ---------------- K0a: x NCHW f32 -> xp padded NHWC bf16 (LDS transpose) ----------------
__global__ __launch_bounds__(256) void k0a(const float* __restrict__ x, bf16* __restrict__ xp){
    __shared__ float lds[64][57];
    int bid = blockIdx.x;
    int n = bid / 224; int rem = bid % 224;
    int y = rem >> 2; int ci0 = (rem & 3) << 6;
    int tid = threadIdx.x;
    for (int e = tid; e < 64*56; e += 256){
        int ci = e / 56, xx = e - ci*56;
        lds[ci][xx] = x[((size_t)((n*C1 + ci0 + ci)*HH) + y)*WW + xx];
    }
    __syncthreads();
    for (int e = tid; e < 64*56; e += 256){
        int xx = e >> 6, ci = e & 63;
        xp[((size_t)(n*XP_H + y + 1)*XP_W + (xx + 1))*C1 + ci0 + ci] = __float2bfloat16(lds[ci][xx]);
    }
}

// ---------------- K0w: cv1 weights -> MFMA B-fragment layout bf16 ----------------
__global__ void k0w(const float* __restrict__ w, bf16* __restrict__ Wf){
    int tlin = blockIdx.x*256 + threadIdx.x;   // 36864 total
    int kt  = tlin >> 9;
    int rem = tlin & 511;
    int nt  = rem >> 6;
    int lane = rem & 63;
    int co = nt*16 + (lane & 15);
    int kbase = kt*32 + (lane >> 4)*8;
    bf16* dst = Wf + (size_t)tlin*8;
    #pragma unroll
    for (int j = 0; j < 8; j++){
        int k = kbase + j;
        int tap = k >> 8;
        int ci  = k & 255;
        dst[j] = __float2bfloat16(w[((size_t)co*C1 + ci)*9 + tap]);
    }
}

// ---------------- K0pack: Wout A-frags, Winp B-frags, Wom B-frags, BN2 scale/bias ----------------
__global__ void k0pack(const float* __restrict__ wout, const float* __restrict__ winp,
                       const float* __restrict__ woff, const float* __restrict__ wmsk,
                       const float* __restrict__ g2, const float* __restrict__ bb2,
                       const float* __restrict__ m2, const float* __restrict__ v2,
                       const float* __restrict__ bout,
                       bf16* __restrict__ Wf2, bf16* __restrict__ Wf3,
                       bf16* __restrict__ Wf4, float* __restrict__ scbi){
    int t = blockIdx.x*256 + threadIdx.x;     // 8192 total
    if (t < 4096){          // Wf2: A-frag wout^T: co=mt*16+(lane&15), k=kc*32+(lane>>4)*8+j
        int lane = t & 63; int kc = (t>>6)&3; int mt = t>>8;
        int co = mt*16 + (lane&15); int k0 = kc*32 + (lane>>4)*8;
        bf16* d = Wf2 + (size_t)t*8;
        #pragma unroll
        for (int j=0;j<8;j++) d[j] = __float2bfloat16(wout[(size_t)(k0+j)*C2 + co]);
    } else if (t < 6144){   // Wf3: B-frag winp: co=nt*16+(lane&15)
        int u = t - 4096; int lane = u&63; int kc=(u>>6)&3; int nt=u>>8;
        int co = nt*16+(lane&15); int k0 = kc*32+(lane>>4)*8;
        bf16* d = Wf3 + (size_t)u*8;
        #pragma unroll
        for (int j=0;j<8;j++) d[j] = __float2bfloat16(winp[(size_t)(k0+j)*CM + co]);
    } else if (t < 7936){   // Wf4: B-frag [woff|wmsk|0]: n=nt*16+(lane&15)
        int u = t - 6144; int lane=u&63; int kc=(u>>6)&3; int nt=u>>8;
        int nn2 = nt*16+(lane&15); int k0 = kc*32+(lane>>4)*8;
        bf16* d = Wf4 + (size_t)u*8;
        #pragma unroll
        for (int j=0;j<8;j++){
            int k = k0+j; float v = 0.f;
            if (nn2 < 72) v = woff[(size_t)k*72 + nn2];
            else if (nn2 < 108) v = wmsk[(size_t)k*36 + (nn2-72)];
            d[j] = __float2bfloat16(v);
        }
    } else if (t < 8192){
        int co = t - 7936;
        float sc = g2[co]*rsqrtf(v2[co]+EPSF);
        scbi[co] = sc;
        scbi[256+co] = bb2[co] - m2[co]*sc + bout[co]*sc;  // fold output-proj bias through BN2
    }
}

// ---------------- K1: implicit-GEMM 3x3 conv via MFMA + BN + SiLU -> hb NHWC bf16 ----------------
__device__ __forceinline__ void stageB(const bf16* __restrict__ Wf, int s, bf16* buf, int w, int lane){
    const bf16* g = Wf + ((size_t)s << 12) + (w << 10) + lane*8;
    bf16* l = buf + (w << 10);
    __builtin_amdgcn_global_load_lds((const __attribute__((address_space(1))) void*)g,
                                     (__attribute__((address_space(3))) void*)l, 16, 0, 0);
    __builtin_amdgcn_global_load_lds((const __attribute__((address_space(1))) void*)(g + 512),
                                     (__attribute__((address_space(3))) void*)(l + 512), 16, 0, 0);
}

__device__ __forceinline__ s16x8 loadA(const bf16* __restrict__ xp, int browbase, int px, int s, int kpart){
    int tap = s >> 3;
    int dy = tap / 3;
    int dx = tap - dy*3;
    int ci0 = (s & 7) << 5;
    size_t off = ((size_t)((browbase + dy) * XP_W) + (px + dx)) * (size_t)C1 + ci0 + kpart*8;
    return *(const s16x8*)(xp + off);
}

__global__ __launch_bounds__(256) void k1_mfma(
    const bf16* __restrict__ xp, const bf16* __restrict__ Wf,
    const float* __restrict__ bg, const float* __restrict__ bb,
    const float* __restrict__ bm, const float* __restrict__ bv,
    bf16* __restrict__ hb)
{
    __shared__ __align__(16) bf16 Bbuf[2][4096];
    int bid = blockIdx.x;
    int n = bid / 112, rem = bid % 112;
    int y = rem >> 1, tile = rem & 1;
    int x0t = tile ? 24 : 0;
    int tid = threadIdx.x, lane = tid & 63;
    int w  = tid >> 6;
    int wm = w & 1, wn = w >> 1;
    int kpart = lane >> 4;
    int pxA = x0t + wm*16 + (lane & 15);
    int browbase = n * XP_H + y;

    f32x4 acc[4] = {{0,0,0,0},{0,0,0,0},{0,0,0,0},{0,0,0,0}};

    stageB(Wf, 0, &Bbuf[0][0], w, lane);
    s16x8 a_cur = loadA(xp, browbase, pxA, 0, kpart);
    __syncthreads();

    for (int s = 0; s < 72; ++s){
        s16x8 a_nxt = a_cur;
        if (s + 1 < 72){
            stageB(Wf, s+1, &Bbuf[(s+1)&1][0], w, lane);
            a_nxt = loadA(xp, browbase, pxA, s+1, kpart);
        }
        const bf16* bufp = &Bbuf[s&1][0] + (wn << 11) + lane*8;
        #pragma unroll
        for (int ct = 0; ct < 4; ++ct){
            s16x8 bfrag = *(const s16x8*)(bufp + (ct << 9));
            acc[ct] = __builtin_amdgcn_mfma_f32_16x16x32_bf16(a_cur, bfrag, acc[ct], 0, 0, 0);
        }
        __syncthreads();
        a_cur = a_nxt;
    }

    int pxO = x0t + wm*16 + kpart*4;
    size_t rowbase = (size_t)n*3136 + (size_t)y*WW;
    #pragma unroll
    for (int ct = 0; ct < 4; ++ct){
        int co = (wn << 6) + (ct << 4) + (lane & 15);
        float sc = bg[co] * rsqrtf(bv[co] + EPSF);
        float bi = bb[co] - bm[co]*sc;
        #pragma unroll
        for (int r = 0; r < 4; ++r){
            float z = acc[ct][r]*sc + bi;
            float sl = z / (1.f + expf(-z));
            hb[(rowbase + pxO + r)*CM + co] = __float2bfloat16(sl);
        }
    }
}

// ---------------- K2: depthwise 3x3 + bias -> LayerNorm(128) -> exact GELU -> tb bf16 ----------------
__global__ __launch_bounds__(128) void k2_dwlngelu(
    const bf16* __restrict__ hb, const float* __restrict__ wdw, const float* __restrict__ bdw,
    const float* __restrict__ lng, const float* __restrict__ lnb, bf16* __restrict__ tb)
{
    int pix = blockIdx.x;
    int n = pix / HWSZ;
    int rem = pix % HWSZ;
    int y = rem / WW, xq = rem % WW;
    int c = threadIdx.x;
    float acc = bdw[c];
    #pragma unroll
    for (int tap = 0; tap < 9; tap++){
        int dy = tap/3, dx = tap%3;
        int yy = y+dy-1, xx = xq+dx-1;
        if (yy>=0 && yy<HH && xx>=0 && xx<WW)
            acc += b2f(hb[((size_t)(n*HH+yy)*WW+xx)*CM + c]) * wdw[c*9+tap];
    }
    float s = acc, ss = acc*acc;
    #pragma unroll
    for (int off=32; off; off>>=1){ s += __shfl_down(s,off); ss += __shfl_down(ss,off); }
    __shared__ float red[4];
    if ((c & 63) == 0){ red[(c>>6)*2] = s; red[(c>>6)*2+1] = ss; }
    __syncthreads();
    float tot  = red[0]+red[2];
    float tots = red[1]+red[3];
    float mean = tot * (1.f/CM);
    float var  = tots*(1.f/CM) - mean*mean;
    var = fmaxf(var, 0.f);
    float z = (acc-mean)*rsqrtf(var+EPSF)*lng[c] + lnb[c];
    float g = 0.5f*z*(1.f + erff(z*0.70710678118654752f));
    tb[(size_t)pix*CM + c] = __float2bfloat16(g);
}

// ---------------- K3: MFMA GEMMs: val = hb x Winp (+binp), om = tb x [Woff|Wmsk] (+bias) ----------------
__global__ __launch_bounds__(256) void k3_gemm(
    const bf16* __restrict__ hb, const bf16* __restrict__ tb,
    const bf16* __restrict__ Wf3, const bf16* __restrict__ Wf4,
    const float* __restrict__ binp, const float* __restrict__ boff, const float* __restrict__ bmsk,
    bf16* __restrict__ val, float* __restrict__ om)
{
    __shared__ __align__(16) bf16 Ah[64*136];
    __shared__ __align__(16) bf16 At[64*136];
    int blk = blockIdx.x;
    int n = blk/49; int p0 = (blk%49)*64;
    size_t pixbase = (size_t)n*3136 + p0;
    int tid = threadIdx.x;
    for (int e = tid; e < 1024; e += 256){
        int row = e>>4, seg = e&15;
        *(s16x8*)&Ah[row*136 + seg*8] = *(const s16x8*)(hb + (pixbase+row)*CM + seg*8);
        *(s16x8*)&At[row*136 + seg*8] = *(const s16x8*)(tb + (pixbase+row)*CM + seg*8);
    }
    __syncthreads();
    int lane = tid & 63, w = tid >> 6;
    int col = lane & 15, kq = lane >> 4;
    int mt = w;
    s16x8 a0[4], a1[4];
    #pragma unroll
    for (int kc=0;kc<4;kc++){
        a0[kc] = *(const s16x8*)&Ah[(mt*16+col)*136 + kc*32 + kq*8];
        a1[kc] = *(const s16x8*)&At[(mt*16+col)*136 + kc*32 + kq*8];
    }
    int pxo = p0 + mt*16 + kq*4;
    #pragma unroll
    for (int nt=0; nt<8; nt++){
        f32x4 acc = {0,0,0,0};
        #pragma unroll
        for (int kc=0;kc<4;kc++){
            s16x8 b = *(const s16x8*)(Wf3 + ((size_t)(nt*4+kc)*64 + lane)*8);
            acc = __builtin_amdgcn_mfma_f32_16x16x32_bf16(a0[kc], b, acc, 0, 0, 0);
        }
        int co = nt*16 + col;
        float bia = binp[co];
        #pragma unroll
        for (int r=0;r<4;r++)
            val[((size_t)n*3136 + pxo + r)*CM + co] = __float2bfloat16(acc[r] + bia);
    }
    #pragma unroll
    for (int nt=0; nt<7; nt++){
        f32x4 acc = {0,0,0,0};
        #pragma unroll
        for (int kc=0;kc<4;kc++){
            s16x8 b = *(const s16x8*)(Wf4 + ((size_t)(nt*4+kc)*64 + lane)*8);
            acc = __builtin_amdgcn_mfma_f32_16x16x32_bf16(a1[kc], b, acc, 0, 0, 0);
        }
        int nn2 = nt*16 + col;
        float bia = (nn2<72) ? boff[nn2] : (nn2<108 ? bmsk[nn2-72] : 0.f);
        #pragma unroll
        for (int r=0;r<4;r++)
            om[((size_t)n*3136 + pxo + r)*112 + nn2] = acc[r] + bia;
    }
}

// ---------------- K4a: softmax + DCNv3 bilinear gather -> o bf16 ----------------
__global__ __launch_bounds__(128) void k4a(
    const bf16* __restrict__ valb, const float* __restrict__ om, bf16* __restrict__ o)
{
    int pix = blockIdx.x;
    int n = pix / HWSZ;
    int rem = pix % HWSZ;
    int y = rem / WW, xq = rem % WW;
    int c = threadIdx.x;
    __shared__ float ob[72], mraw[36], mk[36];
    if (c < 72) ob[c] = om[(size_t)pix*112 + c];
    else if (c < 108) mraw[c-72] = om[(size_t)pix*112 + c];
    __syncthreads();
    if (c < 36){
        int g0 = (c/9)*9;
        float mx = mraw[g0];
        #pragma unroll
        for (int j=1;j<9;j++) mx = fmaxf(mx, mraw[g0+j]);
        float sum = 0.f;
        #pragma unroll
        for (int j=0;j<9;j++) sum += expf(mraw[g0+j]-mx);
        mk[c] = expf(mraw[c]-mx)/sum;
    }
    __syncthreads();
    int g = c >> 5;
    float acc = 0.f;
    #pragma unroll
    for (int k=0;k<9;k++){
        float oxv = ob[g*18 + k*2];
        float oyv = ob[g*18 + k*2 + 1];
        float sx = (float)xq + (float)(k/3) - 1.f + oxv;
        float sy = (float)y  + (float)(k%3) - 1.f + oyv;
        float x0f = floorf(sx), y0f = floorf(sy);
        float fx = sx - x0f, fy = sy - y0f;
        int x0 = (int)x0f, y0 = (int)y0f;
        float mw = mk[g*9+k];
        float w00 = (1.f-fy)*(1.f-fx)*mw;
        float w01 = (1.f-fy)*fx*mw;
        float w10 = fy*(1.f-fx)*mw;
        float w11 = fy*fx*mw;
        if ((unsigned)y0     < HH && (unsigned)x0     < WW) acc += w00*b2f(valb[((size_t)(n*HH+y0  )*WW+x0  )*CM + c]);
        if ((unsigned)y0     < HH && (unsigned)(x0+1) < WW) acc += w01*b2f(valb[((size_t)(n*HH+y0  )*WW+x0+1)*CM + c]);
        if ((unsigned)(y0+1) < HH && (unsigned)x0     < WW) acc += w10*b2f(valb[((size_t)(n*HH+y0+1)*WW+x0  )*CM + c]);
        if ((unsigned)(y0+1) < HH && (unsigned)(x0+1) < WW) acc += w11*b2f(valb[((size_t)(n*HH+y0+1)*WW+x0+1)*CM + c]);
    }
    o[(size_t)pix*CM + c] = __float2bfloat16(acc);
}

// ---------------- K4b: output proj via MFMA (A=Wout^T, B=o^T) + BN2 + SiLU + residual ----------------
__global__ __launch_bounds__(256) void k4b(
    const bf16* __restrict__ o, const bf16* __restrict__ Wf2, const float* __restrict__ scbi,
    const float* __restrict__ xin, float* __restrict__ out)
{
    __shared__ __align__(16) bf16 Bl[64*136];
    int blk = blockIdx.x;
    int n = blk/49; int p0 = (blk%49)*64;
    int tid = threadIdx.x;
    for (int e = tid; e < 1024; e += 256){
        int row = e>>4, seg = e&15;
        *(s16x8*)&Bl[row*136 + seg*8] = *(const s16x8*)(o + ((size_t)n*3136 + p0 + row)*CM + seg*8);
    }
    __syncthreads();
    int lane = tid & 63, w = tid >> 6;
    int col = lane & 15, kq = lane >> 4;
    int co0 = w*64;
    s16x8 af[4][4];
    #pragma unroll
    for (int mt=0;mt<4;mt++)
        #pragma unroll
        for (int kc=0;kc<4;kc++)
            af[mt][kc] = *(const s16x8*)(Wf2 + (((size_t)((co0>>4)+mt)*4 + kc)*64 + lane)*8);
    f32x4 acc[4][4];
    #pragma unroll
    for (int mt=0;mt<4;mt++)
        #pragma unroll
        for (int nt=0;nt<4;nt++)
            acc[mt][nt] = (f32x4){0,0,0,0};
    #pragma unroll
    for (int nt=0;nt<4;nt++){
        s16x8 bfr[4];
        #pragma unroll
        for (int kc=0;kc<4;kc++)
            bfr[kc] = *(const s16x8*)&Bl[(nt*16+col)*136 + kc*32 + kq*8];
        #pragma unroll
        for (int mt=0;mt<4;mt++)
            #pragma unroll
            for (int kc=0;kc<4;kc++)
                acc[mt][nt] = __builtin_amdgcn_mfma_f32_16x16x32_bf16(af[mt][kc], bfr[kc], acc[mt][nt], 0, 0, 0);
    }
    #pragma unroll
    for (int mt=0;mt<4;mt++){
        #pragma unroll
        for (int r=0;r<4;r++){
            int co = co0 + mt*16 + kq*4 + r;
            float sc = scbi[co], bi = scbi[256+co];
            #pragma unroll
            for (int nt=0;nt<4;nt++){
                int px = p0 + nt*16 + col;
                size_t idx = ((size_t)(n*C2 + co))*3136 + px;
                float z = acc[mt][nt][r]*sc + bi;
                float sl = z/(1.f+expf(-z));
                out[idx] = sl + xin[idx];
            }
        }
    }
}

extern "C" void kernel_launch(void* const* d_in, const int* in_sizes, int n_in,
                              void* d_out, int out_size, void* d_ws, size_t ws_size,
                              hipStream_t stream)
{
    const float* x    = (const float*)d_in[0];
    const float* wcv1 = (const float*)d_in[1];
    const float* bn1g = (const float*)d_in[2];
    const float* bn1b = (const float*)d_in[3];
    const float* bn1m = (const float*)d_in[4];
    const float* bn1v = (const float*)d_in[5];
    const float* wdw  = (const float*)d_in[6];
    const float* bdw  = (const float*)d_in[7];
    const float* lng  = (const float*)d_in[8];
    const float* lnb  = (const float*)d_in[9];
    const float* winp = (const float*)d_in[10];
    const float* binp = (const float*)d_in[11];
    const float* woff = (const float*)d_in[12];
    const float* boff = (const float*)d_in[13];
    const float* wmsk = (const float*)d_in[14];
    const float* bmsk = (const float*)d_in[15];
    const float* wout = (const float*)d_in[16];
    const float* bout = (const float*)d_in[17];
    const float* bn2g = (const float*)d_in[18];
    const float* bn2b = (const float*)d_in[19];
    const float* bn2m = (const float*)d_in[20];
    const float* bn2v = (const float*)d_in[21];

    unsigned char* base = (unsigned char*)d_ws;
    bf16*  Wf   = (bf16*)(base);                    //   589,824
    bf16*  Wf2  = (bf16*)(base + 589824);           //    65,536
    bf16*  Wf3  = (bf16*)(base + 655360);           //    32,768
    bf16*  Wf4  = (bf16*)(base + 688128);           //    28,672
    float* scbi = (float*)(base + 716800);          //     2,048
    bf16*  xp   = (bf16*)(base + 718848);           // 13,778,944 (dead after k1; aliased by tb+val)
    bf16*  tb   = (bf16*)(base + 718848);           //  6,422,528
    bf16*  val  = (bf16*)(base + 718848 + 6422528); //  6,422,528
    bf16*  hb   = (bf16*)(base + 14497792);         //  6,422,528
    float* om   = (float*)(base + 20920320);        // 11,239,424
    bf16*  o    = (bf16*)(base + 32159744);         //  6,422,528  (end: 38,582,272)

    const int xp_f4 = (NN*XP_H*XP_W*C1*2) / 16;
    hipLaunchKernelGGL(k0z, dim3((xp_f4+255)/256), dim3(256), 0, stream, (float4*)xp, xp_f4);
    hipLaunchKernelGGL(k0a, dim3(NN*HH*4), dim3(256), 0, stream, x, xp);
    hipLaunchKernelGGL(k0w, dim3(144), dim3(256), 0, stream, wcv1, Wf);
    hipLaunchKernelGGL(k0pack, dim3(32), dim3(256), 0, stream,
                       wout, winp, woff, wmsk, bn2g, bn2b, bn2m, bn2v, bout, Wf2, Wf3, Wf4, scbi);
    hipLaunchKernelGGL(k1_mfma, dim3(NN*HH*2), dim3(256), 0, stream,
                       xp, Wf, bn1g, bn1b, bn1m, bn1v, hb);
    hipLaunchKernelGGL(k2_dwlngelu, dim3(LL), dim3(128), 0, stream,
                       hb, wdw, bdw, lng, lnb, tb);
    hipLaunchKernelGGL(k3_gemm, dim3(NN*49), dim3(256), 0, stream,
                       hb, tb, Wf3, Wf4, binp, boff, bmsk, val, om);
    hipLaunchKernelGGL(k4a, dim3(LL), dim3(128), 0, stream, val, om, o);
    hipLaunchKernelGGL(k4b, dim3(NN*49), dim3(256), 0, stream, o, Wf2, scbi, x, (float*)d_out);
}

// Round 5
// 251.140 us; speedup vs baseline: 3.4358x; 1.2757x over previous
//
#include <hip/hip_runtime.h>
#include <hip/hip_bf16.h>

typedef __hip_bfloat16 bf16;
typedef float f32x4 __attribute__((ext_vector_type(4)));
typedef short s16x8 __attribute__((ext_vector_type(8)));

#define NN 8
#define HH 56
#define WW 56
#define C1 256
#define CM 128
#define C2 256
#define GG 4
#define K2K 9
#define HWSZ (HH*WW)            // 3136
#define LL (NN*HWSZ)            // 25088
#define EPSF 1e-5f
#define XP_H 58
#define XP_W 58

__device__ __forceinline__ float b2f(bf16 v){ return __bfloat162float(v); }

// ---------------- K0z: zero xp (padded NHWC bf16 input) ----------------
__global__ void k0z(float4* __restrict__ p, int n4){
    int i = blockIdx.x*256 + threadIdx.x;
    if (i < n4) p[i] = make_float4(0.f,0.f,0.f,0.f);
}

// ---------------- K0a: x NCHW f32 -> xp padded NHWC bf16 (LDS transpose) ----------------
__global__ __launch_bounds__(256) void k0a(const float* __restrict__ x, bf16* __restrict__ xp){
    __shared__ float lds[64][57];
    int bid = blockIdx.x;
    int n = bid / 224; int rem = bid % 224;
    int y = rem >> 2; int ci0 = (rem & 3) << 6;
    int tid = threadIdx.x;
    for (int e = tid; e < 64*56; e += 256){
        int ci = e / 56, xx = e - ci*56;
        lds[ci][xx] = x[((size_t)((n*C1 + ci0 + ci)*HH) + y)*WW + xx];
    }
    __syncthreads();
    for (int e = tid; e < 64*56; e += 256){
        int xx = e >> 6, ci = e & 63;
        xp[((size_t)(n*XP_H + y + 1)*XP_W + (xx + 1))*C1 + ci0 + ci] = __float2bfloat16(lds[ci][xx]);
    }
}

// ---------------- K0w: cv1 weights -> MFMA B-fragment layout bf16 ----------------
__global__ void k0w(const float* __restrict__ w, bf16* __restrict__ Wf){
    int tlin = blockIdx.x*256 + threadIdx.x;   // 36864 total
    int kt  = tlin >> 9;
    int rem = tlin & 511;
    int nt  = rem >> 6;
    int lane = rem & 63;
    int co = nt*16 + (lane & 15);
    int kbase = kt*32 + (lane >> 4)*8;
    bf16* dst = Wf + (size_t)tlin*8;
    #pragma unroll
    for (int j = 0; j < 8; j++){
        int k = kbase + j;
        int tap = k >> 8;
        int ci  = k & 255;
        dst[j] = __float2bfloat16(w[((size_t)co*C1 + ci)*9 + tap]);
    }
}

// ---------------- K0pack: Wout A-frags, Winp B-frags, Wom B-frags, BN2 scale/bias, wdwT ----------------
__global__ void k0pack(const float* __restrict__ wout, const float* __restrict__ winp,
                       const float* __restrict__ woff, const float* __restrict__ wmsk,
                       const float* __restrict__ g2, const float* __restrict__ bb2,
                       const float* __restrict__ m2, const float* __restrict__ v2,
                       const float* __restrict__ bout, const float* __restrict__ wdw,
                       bf16* __restrict__ Wf2, bf16* __restrict__ Wf3,
                       bf16* __restrict__ Wf4, float* __restrict__ scbi,
                       float* __restrict__ wdwT){
    int t = blockIdx.x*256 + threadIdx.x;     // 9344 total
    if (t < 4096){          // Wf2: A-frag wout^T: co=mt*16+(lane&15), k=kc*32+(lane>>4)*8+j
        int lane = t & 63; int kc = (t>>6)&3; int mt = t>>8;
        int co = mt*16 + (lane&15); int k0 = kc*32 + (lane>>4)*8;
        bf16* d = Wf2 + (size_t)t*8;
        #pragma unroll
        for (int j=0;j<8;j++) d[j] = __float2bfloat16(wout[(size_t)(k0+j)*C2 + co]);
    } else if (t < 6144){   // Wf3: B-frag winp: co=nt*16+(lane&15)
        int u = t - 4096; int lane = u&63; int kc=(u>>6)&3; int nt=u>>8;
        int co = nt*16+(lane&15); int k0 = kc*32+(lane>>4)*8;
        bf16* d = Wf3 + (size_t)u*8;
        #pragma unroll
        for (int j=0;j<8;j++) d[j] = __float2bfloat16(winp[(size_t)(k0+j)*CM + co]);
    } else if (t < 7936){   // Wf4: B-frag [woff|wmsk|0]: n=nt*16+(lane&15)
        int u = t - 6144; int lane=u&63; int kc=(u>>6)&3; int nt=u>>8;
        int nn2 = nt*16+(lane&15); int k0 = kc*32+(lane>>4)*8;
        bf16* d = Wf4 + (size_t)u*8;
        #pragma unroll
        for (int j=0;j<8;j++){
            int k = k0+j; float v = 0.f;
            if (nn2 < 72) v = woff[(size_t)k*72 + nn2];
            else if (nn2 < 108) v = wmsk[(size_t)k*36 + (nn2-72)];
            d[j] = __float2bfloat16(v);
        }
    } else if (t < 8192){
        int co = t - 7936;
        float sc = g2[co]*rsqrtf(v2[co]+EPSF);
        scbi[co] = sc;
        scbi[256+co] = bb2[co] - m2[co]*sc + bout[co]*sc;  // fold output-proj bias through BN2
    } else if (t < 8192 + 9*CM){
        int u = t - 8192;
        int tap = u >> 7, c = u & 127;
        wdwT[tap*CM + c] = wdw[c*9 + tap];
    }
}

// ---------------- K1: implicit-GEMM 3x3 conv via MFMA + BN + SiLU -> hb NHWC bf16 ----------------
__device__ __forceinline__ void stageB(const bf16* __restrict__ Wf, int s, bf16* buf, int w, int lane){
    const bf16* g = Wf + ((size_t)s << 12) + (w << 10) + lane*8;
    bf16* l = buf + (w << 10);
    __builtin_amdgcn_global_load_lds((const __attribute__((address_space(1))) void*)g,
                                     (__attribute__((address_space(3))) void*)l, 16, 0, 0);
    __builtin_amdgcn_global_load_lds((const __attribute__((address_space(1))) void*)(g + 512),
                                     (__attribute__((address_space(3))) void*)(l + 512), 16, 0, 0);
}

__device__ __forceinline__ s16x8 loadA(const bf16* __restrict__ xp, int browbase, int px, int s, int kpart){
    int tap = s >> 3;
    int dy = tap / 3;
    int dx = tap - dy*3;
    int ci0 = (s & 7) << 5;
    size_t off = ((size_t)((browbase + dy) * XP_W) + (px + dx)) * (size_t)C1 + ci0 + kpart*8;
    return *(const s16x8*)(xp + off);
}

__global__ __launch_bounds__(256) void k1_mfma(
    const bf16* __restrict__ xp, const bf16* __restrict__ Wf,
    const float* __restrict__ bg, const float* __restrict__ bb,
    const float* __restrict__ bm, const float* __restrict__ bv,
    bf16* __restrict__ hb)
{
    __shared__ __align__(16) bf16 Bbuf[2][4096];
    int bid = blockIdx.x;
    int n = bid / 112, rem = bid % 112;
    int y = rem >> 1, tile = rem & 1;
    int x0t = tile ? 24 : 0;
    int tid = threadIdx.x, lane = tid & 63;
    int w  = tid >> 6;
    int wm = w & 1, wn = w >> 1;
    int kpart = lane >> 4;
    int pxA = x0t + wm*16 + (lane & 15);
    int browbase = n * XP_H + y;

    f32x4 acc[4] = {{0,0,0,0},{0,0,0,0},{0,0,0,0},{0,0,0,0}};

    stageB(Wf, 0, &Bbuf[0][0], w, lane);
    s16x8 a_cur = loadA(xp, browbase, pxA, 0, kpart);
    __syncthreads();

    for (int s = 0; s < 72; ++s){
        s16x8 a_nxt = a_cur;
        if (s + 1 < 72){
            stageB(Wf, s+1, &Bbuf[(s+1)&1][0], w, lane);
            a_nxt = loadA(xp, browbase, pxA, s+1, kpart);
        }
        const bf16* bufp = &Bbuf[s&1][0] + (wn << 11) + lane*8;
        #pragma unroll
        for (int ct = 0; ct < 4; ++ct){
            s16x8 bfrag = *(const s16x8*)(bufp + (ct << 9));
            acc[ct] = __builtin_amdgcn_mfma_f32_16x16x32_bf16(a_cur, bfrag, acc[ct], 0, 0, 0);
        }
        __syncthreads();
        a_cur = a_nxt;
    }

    int pxO = x0t + wm*16 + kpart*4;
    size_t rowbase = (size_t)n*3136 + (size_t)y*WW;
    #pragma unroll
    for (int ct = 0; ct < 4; ++ct){
        int co = (wn << 6) + (ct << 4) + (lane & 15);
        float sc = bg[co] * rsqrtf(bv[co] + EPSF);
        float bi = bb[co] - bm[co]*sc;
        #pragma unroll
        for (int r = 0; r < 4; ++r){
            float z = acc[ct][r]*sc + bi;
            float sl = z / (1.f + expf(-z));
            hb[(rowbase + pxO + r)*CM + co] = __float2bfloat16(sl);
        }
    }
}

// ---------------- K2: depthwise 3x3 + LN + GELU, 8 pixels/block, 16B loads ----------------
__global__ __launch_bounds__(128) void k2v(
    const bf16* __restrict__ hb, const float* __restrict__ wdwT, const float* __restrict__ bdw,
    const float* __restrict__ lng, const float* __restrict__ lnb, bf16* __restrict__ tb)
{
    int t = threadIdx.x;
    int p = t >> 4, s = t & 15;
    int pix = blockIdx.x*8 + p;
    int n = pix / HWSZ, rem = pix % HWSZ;
    int y = rem / WW, xq = rem % WW;
    int c0 = s*8;
    const bf16* hbase = hb + (size_t)n*HWSZ*CM;
    float acc[8];
    {
        float4 b0 = *(const float4*)(bdw + c0);
        float4 b1 = *(const float4*)(bdw + c0 + 4);
        acc[0]=b0.x; acc[1]=b0.y; acc[2]=b0.z; acc[3]=b0.w;
        acc[4]=b1.x; acc[5]=b1.y; acc[6]=b1.z; acc[7]=b1.w;
    }
    #pragma unroll
    for (int tap=0; tap<9; tap++){
        int dy=tap/3, dx=tap%3;
        int yy=y+dy-1, xx=xq+dx-1;
        if ((unsigned)yy < HH && (unsigned)xx < WW){
            s16x8 v = *(const s16x8*)(hbase + ((size_t)(yy*WW+xx))*CM + c0);
            float4 w0 = *(const float4*)(wdwT + tap*CM + c0);
            float4 w1 = *(const float4*)(wdwT + tap*CM + c0 + 4);
            float wv[8] = {w0.x,w0.y,w0.z,w0.w,w1.x,w1.y,w1.z,w1.w};
            #pragma unroll
            for (int j=0;j<8;j++)
                acc[j] += b2f(((bf16*)&v)[j]) * wv[j];
        }
    }
    float s1=0.f, s2=0.f;
    #pragma unroll
    for (int j=0;j<8;j++){ s1 += acc[j]; s2 += acc[j]*acc[j]; }
    #pragma unroll
    for (int off=1; off<16; off<<=1){
        s1 += __shfl_xor(s1, off);
        s2 += __shfl_xor(s2, off);
    }
    float mean = s1*(1.f/CM);
    float var  = fmaxf(s2*(1.f/CM) - mean*mean, 0.f);
    float inv  = rsqrtf(var + EPSF);
    float4 g0 = *(const float4*)(lng + c0); float4 g1 = *(const float4*)(lng + c0+4);
    float4 q0 = *(const float4*)(lnb + c0); float4 q1 = *(const float4*)(lnb + c0+4);
    float gv[8]={g0.x,g0.y,g0.z,g0.w,g1.x,g1.y,g1.z,g1.w};
    float qv[8]={q0.x,q0.y,q0.z,q0.w,q1.x,q1.y,q1.z,q1.w};
    s16x8 ov;
    #pragma unroll
    for (int j=0;j<8;j++){
        float z = (acc[j]-mean)*inv*gv[j] + qv[j];
        float gl = 0.5f*z*(1.f + erff(z*0.70710678118654752f));
        ((bf16*)&ov)[j] = __float2bfloat16(gl);
    }
    *(s16x8*)(tb + (size_t)pix*CM + c0) = ov;
}

// ---------------- K3: MFMA GEMMs: val = hb x Winp (+binp), om = tb x [Woff|Wmsk] (+bias) ----------------
__global__ __launch_bounds__(256) void k3_gemm(
    const bf16* __restrict__ hb, const bf16* __restrict__ tb,
    const bf16* __restrict__ Wf3, const bf16* __restrict__ Wf4,
    const float* __restrict__ binp, const float* __restrict__ boff, const float* __restrict__ bmsk,
    bf16* __restrict__ val, float* __restrict__ om)
{
    __shared__ __align__(16) bf16 Ah[64*136];
    __shared__ __align__(16) bf16 At[64*136];
    int blk = blockIdx.x;
    int n = blk/49; int p0 = (blk%49)*64;
    size_t pixbase = (size_t)n*3136 + p0;
    int tid = threadIdx.x;
    for (int e = tid; e < 1024; e += 256){
        int row = e>>4, seg = e&15;
        *(s16x8*)&Ah[row*136 + seg*8] = *(const s16x8*)(hb + (pixbase+row)*CM + seg*8);
        *(s16x8*)&At[row*136 + seg*8] = *(const s16x8*)(tb + (pixbase+row)*CM + seg*8);
    }
    __syncthreads();
    int lane = tid & 63, w = tid >> 6;
    int col = lane & 15, kq = lane >> 4;
    int mt = w;
    s16x8 a0[4], a1[4];
    #pragma unroll
    for (int kc=0;kc<4;kc++){
        a0[kc] = *(const s16x8*)&Ah[(mt*16+col)*136 + kc*32 + kq*8];
        a1[kc] = *(const s16x8*)&At[(mt*16+col)*136 + kc*32 + kq*8];
    }
    int pxo = p0 + mt*16 + kq*4;
    #pragma unroll
    for (int nt=0; nt<8; nt++){
        f32x4 acc = {0,0,0,0};
        #pragma unroll
        for (int kc=0;kc<4;kc++){
            s16x8 b = *(const s16x8*)(Wf3 + ((size_t)(nt*4+kc)*64 + lane)*8);
            acc = __builtin_amdgcn_mfma_f32_16x16x32_bf16(a0[kc], b, acc, 0, 0, 0);
        }
        int co = nt*16 + col;
        float bia = binp[co];
        #pragma unroll
        for (int r=0;r<4;r++)
            val[((size_t)n*3136 + pxo + r)*CM + co] = __float2bfloat16(acc[r] + bia);
    }
    #pragma unroll
    for (int nt=0; nt<7; nt++){
        f32x4 acc = {0,0,0,0};
        #pragma unroll
        for (int kc=0;kc<4;kc++){
            s16x8 b = *(const s16x8*)(Wf4 + ((size_t)(nt*4+kc)*64 + lane)*8);
            acc = __builtin_amdgcn_mfma_f32_16x16x32_bf16(a1[kc], b, acc, 0, 0, 0);
        }
        int nn2 = nt*16 + col;
        float bia = (nn2<72) ? boff[nn2] : (nn2<108 ? bmsk[nn2-72] : 0.f);
        #pragma unroll
        for (int r=0;r<4;r++)
            om[((size_t)n*3136 + pxo + r)*112 + nn2] = acc[r] + bia;
    }
}

// ---------------- K4a: softmax + DCNv3 bilinear gather, 8 pixels/block, 16B loads ----------------
__global__ __launch_bounds__(128) void k4a(
    const bf16* __restrict__ valb, const float* __restrict__ om, bf16* __restrict__ o)
{
    __shared__ float omb[8][112];
    __shared__ float mk[8][36];
    int t = threadIdx.x;
    int pix0 = blockIdx.x*8;
    for (int e = t; e < 8*112; e += 128){
        int p = e / 112, q = e - (e/112)*112;
        omb[p][q] = om[(size_t)(pix0+p)*112 + q];
    }
    __syncthreads();
    if (t < 32){
        int p = t >> 2, g = t & 3;
        float mx = omb[p][72+g*9];
        #pragma unroll
        for (int j=1;j<9;j++) mx = fmaxf(mx, omb[p][72+g*9+j]);
        float sum=0.f; float e9[9];
        #pragma unroll
        for (int j=0;j<9;j++){ e9[j] = expf(omb[p][72+g*9+j]-mx); sum += e9[j]; }
        float inv = 1.f/sum;
        #pragma unroll
        for (int j=0;j<9;j++) mk[p][g*9+j] = e9[j]*inv;
    }
    __syncthreads();
    int p = t >> 4, s = t & 15;
    int g = s >> 2;
    int c0 = s*8;
    int pix = pix0 + p;
    int n = pix / HWSZ, rem = pix % HWSZ;
    int y = rem / WW, xq = rem % WW;
    const bf16* vb = valb + (size_t)n*HWSZ*CM;
    float acc[8] = {0,0,0,0,0,0,0,0};
    #pragma unroll
    for (int k=0;k<9;k++){
        float oxv = omb[p][g*18 + k*2];
        float oyv = omb[p][g*18 + k*2 + 1];
        float sx = (float)xq + (float)(k/3) - 1.f + oxv;
        float sy = (float)y  + (float)(k%3) - 1.f + oyv;
        float x0f = floorf(sx), y0f = floorf(sy);
        float fx = sx - x0f, fy = sy - y0f;
        int x0 = (int)x0f, y0 = (int)y0f;
        float mw = mk[p][g*9+k];
        float w00 = (1.f-fy)*(1.f-fx)*mw;
        float w01 = (1.f-fy)*fx*mw;
        float w10 = fy*(1.f-fx)*mw;
        float w11 = fy*fx*mw;
        if ((unsigned)y0 < HH && (unsigned)x0 < WW){
            s16x8 v = *(const s16x8*)(vb + ((size_t)(y0*WW+x0))*CM + c0);
            #pragma unroll
            for (int j=0;j<8;j++) acc[j] += w00*b2f(((bf16*)&v)[j]);
        }
        if ((unsigned)y0 < HH && (unsigned)(x0+1) < WW){
            s16x8 v = *(const s16x8*)(vb + ((size_t)(y0*WW+x0+1))*CM + c0);
            #pragma unroll
            for (int j=0;j<8;j++) acc[j] += w01*b2f(((bf16*)&v)[j]);
        }
        if ((unsigned)(y0+1) < HH && (unsigned)x0 < WW){
            s16x8 v = *(const s16x8*)(vb + ((size_t)((y0+1)*WW+x0))*CM + c0);
            #pragma unroll
            for (int j=0;j<8;j++) acc[j] += w10*b2f(((bf16*)&v)[j]);
        }
        if ((unsigned)(y0+1) < HH && (unsigned)(x0+1) < WW){
            s16x8 v = *(const s16x8*)(vb + ((size_t)((y0+1)*WW+x0+1))*CM + c0);
            #pragma unroll
            for (int j=0;j<8;j++) acc[j] += w11*b2f(((bf16*)&v)[j]);
        }
    }
    s16x8 ov;
    #pragma unroll
    for (int j=0;j<8;j++) ((bf16*)&ov)[j] = __float2bfloat16(acc[j]);
    *(s16x8*)(o + (size_t)pix*CM + c0) = ov;
}

// ---------------- K4b: output proj via MFMA (A=Wout^T, B=o^T) + BN2 + SiLU + residual ----------------
__global__ __launch_bounds__(256) void k4b(
    const bf16* __restrict__ o, const bf16* __restrict__ Wf2, const float* __restrict__ scbi,
    const float* __restrict__ xin, float* __restrict__ out)
{
    __shared__ __align__(16) bf16 Bl[64*136];
    int blk = blockIdx.x;
    int n = blk/49; int p0 = (blk%49)*64;
    int tid = threadIdx.x;
    for (int e = tid; e < 1024; e += 256){
        int row = e>>4, seg = e&15;
        *(s16x8*)&Bl[row*136 + seg*8] = *(const s16x8*)(o + ((size_t)n*3136 + p0 + row)*CM + seg*8);
    }
    __syncthreads();
    int lane = tid & 63, w = tid >> 6;
    int col = lane & 15, kq = lane >> 4;
    int co0 = w*64;
    s16x8 af[4][4];
    #pragma unroll
    for (int mt=0;mt<4;mt++)
        #pragma unroll
        for (int kc=0;kc<4;kc++)
            af[mt][kc] = *(const s16x8*)(Wf2 + (((size_t)((co0>>4)+mt)*4 + kc)*64 + lane)*8);
    f32x4 acc[4][4];
    #pragma unroll
    for (int mt=0;mt<4;mt++)
        #pragma unroll
        for (int nt=0;nt<4;nt++)
            acc[mt][nt] = (f32x4){0,0,0,0};
    #pragma unroll
    for (int nt=0;nt<4;nt++){
        s16x8 bfr[4];
        #pragma unroll
        for (int kc=0;kc<4;kc++)
            bfr[kc] = *(const s16x8*)&Bl[(nt*16+col)*136 + kc*32 + kq*8];
        #pragma unroll
        for (int mt=0;mt<4;mt++)
            #pragma unroll
            for (int kc=0;kc<4;kc++)
                acc[mt][nt] = __builtin_amdgcn_mfma_f32_16x16x32_bf16(af[mt][kc], bfr[kc], acc[mt][nt], 0, 0, 0);
    }
    #pragma unroll
    for (int mt=0;mt<4;mt++){
        #pragma unroll
        for (int r=0;r<4;r++){
            int co = co0 + mt*16 + kq*4 + r;
            float sc = scbi[co], bi = scbi[256+co];
            #pragma unroll
            for (int nt=0;nt<4;nt++){
                int px = p0 + nt*16 + col;
                size_t idx = ((size_t)(n*C2 + co))*3136 + px;
                float z = acc[mt][nt][r]*sc + bi;
                float sl = z/(1.f+expf(-z));
                out[idx] = sl + xin[idx];
            }
        }
    }
}

extern "C" void kernel_launch(void* const* d_in, const int* in_sizes, int n_in,
                              void* d_out, int out_size, void* d_ws, size_t ws_size,
                              hipStream_t stream)
{
    const float* x    = (const float*)d_in[0];
    const float* wcv1 = (const float*)d_in[1];
    const float* bn1g = (const float*)d_in[2];
    const float* bn1b = (const float*)d_in[3];
    const float* bn1m = (const float*)d_in[4];
    const float* bn1v = (const float*)d_in[5];
    const float* wdw  = (const float*)d_in[6];
    const float* bdw  = (const float*)d_in[7];
    const float* lng  = (const float*)d_in[8];
    const float* lnb  = (const float*)d_in[9];
    const float* winp = (const float*)d_in[10];
    const float* binp = (const float*)d_in[11];
    const float* woff = (const float*)d_in[12];
    const float* boff = (const float*)d_in[13];
    const float* wmsk = (const float*)d_in[14];
    const float* bmsk = (const float*)d_in[15];
    const float* wout = (const float*)d_in[16];
    const float* bout = (const float*)d_in[17];
    const float* bn2g = (const float*)d_in[18];
    const float* bn2b = (const float*)d_in[19];
    const float* bn2m = (const float*)d_in[20];
    const float* bn2v = (const float*)d_in[21];

    unsigned char* base = (unsigned char*)d_ws;
    bf16*  Wf   = (bf16*)(base);                    //       0 +   589,824
    bf16*  Wf2  = (bf16*)(base + 589824);           //          65,536
    bf16*  Wf3  = (bf16*)(base + 655360);           //          32,768
    bf16*  Wf4  = (bf16*)(base + 688128);           //          28,672
    float* scbi = (float*)(base + 716800);          //           2,048
    float* wdwT = (float*)(base + 718848);          //           4,608
    bf16*  xp   = (bf16*)(base + 723456);           //      13,778,944 (dead after k1; aliased by tb+val)
    bf16*  tb   = (bf16*)(base + 723456);           //       6,422,528
    bf16*  val  = (bf16*)(base + 7145984);          //       6,422,528 (ends 13,568,512 < xp end 14,502,400)
    bf16*  hb   = (bf16*)(base + 14502400);         //       6,422,528
    float* om   = (float*)(base + 20924928);        //      11,239,424
    bf16*  o    = (bf16*)(base + 32164352);         //       6,422,528 (end 38,586,880)

    const int xp_f4 = (NN*XP_H*XP_W*C1*2) / 16;
    hipLaunchKernelGGL(k0z, dim3((xp_f4+255)/256), dim3(256), 0, stream, (float4*)xp, xp_f4);
    hipLaunchKernelGGL(k0a, dim3(NN*HH*4), dim3(256), 0, stream, x, xp);
    hipLaunchKernelGGL(k0w, dim3(144), dim3(256), 0, stream, wcv1, Wf);
    hipLaunchKernelGGL(k0pack, dim3(37), dim3(256), 0, stream,
                       wout, winp, woff, wmsk, bn2g, bn2b, bn2m, bn2v, bout, wdw,
                       Wf2, Wf3, Wf4, scbi, wdwT);
    hipLaunchKernelGGL(k1_mfma, dim3(NN*HH*2), dim3(256), 0, stream,
                       xp, Wf, bn1g, bn1b, bn1m, bn1v, hb);
    hipLaunchKernelGGL(k2v, dim3(LL/8), dim3(128), 0, stream,
                       hb, wdwT, bdw, lng, lnb, tb);
    hipLaunchKernelGGL(k3_gemm, dim3(NN*49), dim3(256), 0, stream,
                       hb, tb, Wf3, Wf4, binp, boff, bmsk, val, om);
    hipLaunchKernelGGL(k4a, dim3(LL/8), dim3(128), 0, stream, val, om, o);
    hipLaunchKernelGGL(k4b, dim3(NN*49), dim3(256), 0, stream, o, Wf2, scbi, x, (float*)d_out);
}